// Round 8
// baseline (254.818 us; speedup 1.0000x reference)
//
#include <hip/hip_runtime.h>
#include <cstddef>

// SASRec inference. Round 8: k_score write-locality restructure — block =
// (item_tile, batch_chunk) with batch_chunk INNER in blockIdx so resident
// blocks write adjacent columns of the same rows (DRAM page locality).
// T pre-packed once into fragment-ordered bf16 hi/lo (k_pack); E packed in
// k_layers (final LN fused there; k_lnf eliminated). Math bit-identical.

#define NITEMS 200000
#define Bsz 512
#define Ssz 64
#define Dsz 64
#define EPSV 1e-3f
#define NEGV (-4294967295.0f)   // -2^32 + 1

typedef __attribute__((ext_vector_type(8))) short short8;   // 8 bf16
typedef __attribute__((ext_vector_type(4))) float f32x4;
typedef unsigned short ushort_t;

static __device__ __forceinline__ float wsum(float v){
#pragma unroll
  for (int o = 32; o > 0; o >>= 1) v += __shfl_xor(v, o, 64);
  return v;
}
static __device__ __forceinline__ float wmax(float v){
#pragma unroll
  for (int o = 32; o > 0; o >>= 1) v = fmaxf(v, __shfl_xor(v, o, 64));
  return v;
}

// bf16 round-to-nearest-even (finite inputs only)
static __device__ __forceinline__ ushort_t f2b(float f){
  unsigned u = __float_as_uint(f);
  unsigned r = u + 0x7fffu + ((u >> 16) & 1u);
  return (ushort_t)(r >> 16);
}
static __device__ __forceinline__ float b2f(ushort_t h){
  return __uint_as_float(((unsigned)h) << 16);
}

// ---------------------------------------------------------------- embed ----
__global__ __launch_bounds__(256) void k_embed(const int* __restrict__ ids,
    const float* __restrict__ item_emb, const float* __restrict__ pos_emb,
    float* __restrict__ seq){
  int e4 = blockIdx.x * 256 + threadIdx.x;      // float4 index over [B*S][16]
  int d4 = e4 & 15, bs = e4 >> 4, s = bs & 63;
  int id = ids[bs];
  float4 r = make_float4(0.f, 0.f, 0.f, 0.f);
  if (id != NITEMS){
    float4 a = ((const float4*)(item_emb + (size_t)id * 64))[d4];
    float4 p = ((const float4*)(pos_emb + s * 64))[d4];
    r = make_float4(a.x + p.x, a.y + p.y, a.z + p.z, a.w + p.w);
  }
  ((float4*)seq)[e4] = r;
}

// ----------------------------------------------------------------- pack ----
// Pre-convert item table T (f32 [200000][64]) into MFMA B-fragment order:
// per 64-item tile it: slot q=nt*2+kc (hi) / 8+nt*2+kc (lo), 64 lanes x 16B.
// Tp[it*1024 + slot*64 + lane] (short8) = T[i0+nt*16+(lane&15)]
//                                           [kc*32+(lane>>4)*8 .. +7]
__global__ __launch_bounds__(256) void k_pack(const float* __restrict__ T,
    short8* __restrict__ Tp){
  __shared__ float F[64][68];
  const int t = threadIdx.x;
  const int it = blockIdx.x, i0 = it * 64;
#pragma unroll
  for (int i = 0; i < 4; ++i){
    int e4 = t + 256 * i;
    int r = e4 >> 4, c4 = e4 & 15;
    float4 v = ((const float4*)(T + (size_t)(i0 + r) * 64))[c4];
    *(float4*)&F[r][c4 * 4] = v;
  }
  __syncthreads();
  const int lane = t & 63, p = t >> 6;
  const int li = lane & 15, g = lane >> 4;
#pragma unroll
  for (int s = 0; s < 2; ++s){
    int cc = p + s * 4;
    int nt = cc >> 1, kc = cc & 1;
    short8 h, l;
#pragma unroll
    for (int j = 0; j < 8; ++j){
      float f = F[nt*16 + li][kc*32 + g*8 + j];
      ushort_t hh = f2b(f);
      h[j] = (short)hh;
      l[j] = (short)f2b(f - b2f(hh));
    }
    Tp[(size_t)it*1024 + (nt*2 + kc)*64 + lane] = h;
    Tp[(size_t)it*1024 + 512 + (nt*2 + kc)*64 + lane] = l;
  }
}

// ------------------------------------------------------ fused block layers --
static __device__ __forceinline__ void stage_w1024(ushort_t WH[64][72],
    ushort_t WL[64][72], float4 r0, int t){
  __syncthreads();                 // fence previous consumers of WH/WL
  int k0 = t >> 4, n0 = (t & 15) * 4;
  float f0[4] = {r0.x, r0.y, r0.z, r0.w};
#pragma unroll
  for (int j = 0; j < 4; ++j){
    ushort_t h = f2b(f0[j]);
    WH[n0 + j][k0] = h;
    WL[n0 + j][k0] = f2b(f0[j] - b2f(h));
  }
  __syncthreads();
}

static __device__ __forceinline__ void mm16(
    const ushort_t (*__restrict__ Ah)[72], const ushort_t (*__restrict__ Al)[72],
    const ushort_t (*__restrict__ Bh)[72], const ushort_t (*__restrict__ Bl)[72],
    int qb, int cb, int li, int g, f32x4& acc){
  acc = (f32x4)(0.f);
#pragma unroll
  for (int kc = 0; kc < 2; ++kc){
    short8 ah = *(const short8*)&Ah[qb*16 + li][kc*32 + g*8];
    short8 al = *(const short8*)&Al[qb*16 + li][kc*32 + g*8];
    short8 bh = *(const short8*)&Bh[cb*16 + li][kc*32 + g*8];
    short8 bl = *(const short8*)&Bl[cb*16 + li][kc*32 + g*8];
    acc = __builtin_amdgcn_mfma_f32_16x16x32_bf16(ah, bh, acc, 0, 0, 0);
    acc = __builtin_amdgcn_mfma_f32_16x16x32_bf16(ah, bl, acc, 0, 0, 0);
    acc = __builtin_amdgcn_mfma_f32_16x16x32_bf16(al, bh, acc, 0, 0, 0);
  }
}

__global__ __launch_bounds__(1024) void k_layers(const float* __restrict__ seq_g,
    const int* __restrict__ ids,
    const float* __restrict__ ln1g, const float* __restrict__ ln1b,
    const float* __restrict__ Wq, const float* __restrict__ bq,
    const float* __restrict__ Wk, const float* __restrict__ bk,
    const float* __restrict__ Wv, const float* __restrict__ bv,
    const float* __restrict__ ln2g, const float* __restrict__ ln2b,
    const float* __restrict__ W1, const float* __restrict__ b1,
    const float* __restrict__ W2, const float* __restrict__ b2,
    const float* __restrict__ lnfg, const float* __restrict__ lnfb,
    ushort_t* __restrict__ Eh, ushort_t* __restrict__ El){
  __shared__ float F0[64][68];   // seq -> scores -> x -> layer-out (f32)
  __shared__ float F1[64][68];   // LN1/LN2 residuals
  __shared__ ushort_t UH[5][64][72], UL[5][64][72];
  __shared__ ushort_t WH[64][72], WL[64][72];
  __shared__ float s_msk[64];

  const int t = threadIdx.x;
  const int lane = t & 63, wid = t >> 6;        // 16 waves
  const int li = lane & 15, g = lane >> 4;
  const int qb = wid & 3, cb = wid >> 2;
  const int b = blockIdx.x;
  const float* seq_b = seq_g + (size_t)b * Ssz * Dsz;

  // ---- phase 0: load seq -> F0 (f32) + U0 (bf16 h/l) ----
  {
    int r = t >> 4, c = (t & 15) * 4;
    float4 v = ((const float4*)seq_b)[t];
    *(float4*)&F0[r][c] = v;
    float f[4] = {v.x, v.y, v.z, v.w};
#pragma unroll
    for (int j = 0; j < 4; ++j){
      ushort_t h = f2b(f[j]);
      UH[0][r][c + j] = h;
      UL[0][r][c + j] = f2b(f[j] - b2f(h));
    }
  }
  if (t < 64) s_msk[t] = (ids[b * Ssz + t] != NITEMS) ? 1.f : 0.f;

  const int k0 = t >> 4, n0 = (t & 15) * 4;

  for (int l = 0; l < 2; ++l){
    float4 w_q = *(const float4*)&Wq[l*4096 + k0*64 + n0];
    float4 w_k = *(const float4*)&Wk[l*4096 + k0*64 + n0];
    float4 w_v = *(const float4*)&Wv[l*4096 + k0*64 + n0];
    float4 w_1 = *(const float4*)&W1[l*4096 + k0*64 + n0];
    float4 w_2 = *(const float4*)&W2[l*4096 + k0*64 + n0];

    __syncthreads();

    // ---- LN1 ----
    for (int r = wid; r < 64; r += 16){
      float x = F0[r][lane];
      float mu = wsum(x) * (1.f / 64.f);
      float dv = x - mu;
      float var = wsum(dv * dv) * (1.f / 64.f);
      float o = dv * (1.f / sqrtf(var + EPSV)) * ln1g[l*64 + lane] + ln1b[l*64 + lane];
      F1[r][lane] = o;
      ushort_t h = f2b(o);
      UH[1][r][lane] = h;
      UL[1][r][lane] = f2b(o - b2f(h));
    }

    // ---- Q ----
    stage_w1024(WH, WL, w_q, t);
    { f32x4 acc; mm16(UH[1], UL[1], WH, WL, qb, cb, li, g, acc);
      int col = cb*16 + li;
      float bb = bq[l*64 + col];
#pragma unroll
      for (int r4 = 0; r4 < 4; ++r4){
        int row = qb*16 + g*4 + r4;
        float qv = acc[r4] + bb;
        ushort_t h = f2b(qv);
        UH[2][row][col] = h; UL[2][row][col] = f2b(qv - b2f(h));
      }
    }
    // ---- K ----
    stage_w1024(WH, WL, w_k, t);
    { f32x4 acc; mm16(UH[0], UL[0], WH, WL, qb, cb, li, g, acc);
      int col = cb*16 + li;
      float bb = bk[l*64 + col];
#pragma unroll
      for (int r4 = 0; r4 < 4; ++r4){
        int row = qb*16 + g*4 + r4;
        float kv = acc[r4] + bb;
        ushort_t h = f2b(kv);
        UH[3][row][col] = h; UL[3][row][col] = f2b(kv - b2f(h));
      }
    }
    // ---- V (transposed) ----
    stage_w1024(WH, WL, w_v, t);
    { f32x4 acc; mm16(UH[0], UL[0], WH, WL, qb, cb, li, g, acc);
      int col = cb*16 + li;
      float bb = bv[l*64 + col];
#pragma unroll
      for (int r4 = 0; r4 < 4; ++r4){
        int row = qb*16 + g*4 + r4;
        float vv = acc[r4] + bb;
        ushort_t h = f2b(vv);
        UH[4][col][row] = h; UL[4][col][row] = f2b(vv - b2f(h));
      }
    }
    __syncthreads();

    // ---- scores ----
    { f32x4 acc; mm16(UH[2], UL[2], UH[3], UL[3], qb, cb, li, g, acc);
      int col = cb*16 + li;
#pragma unroll
      for (int r4 = 0; r4 < 4; ++r4)
        F0[qb*16 + g*4 + r4][col] = acc[r4];
    }
    __syncthreads();

    // ---- masked softmax ----
    for (int r = wid; r < 64; r += 16){
      float raw = F0[r][lane];
      bool valid = (lane <= r) && (s_msk[lane] != 0.f);
      float sc = valid ? raw * 0.125f : NEGV;
      float m = wmax(sc);
      float e = __expf(sc - m);
      float ssumv = wsum(e);
      float p = (e / ssumv) * s_msk[r];
      ushort_t h = f2b(p);
      UH[0][r][lane] = h;
      UL[0][r][lane] = f2b(p - b2f(h));
    }
    __syncthreads();

    // ---- x = P @ V + xq ----
    { f32x4 acc; mm16(UH[0], UL[0], UH[4], UL[4], qb, cb, li, g, acc);
      int col = cb*16 + li;
#pragma unroll
      for (int r4 = 0; r4 < 4; ++r4){
        int row = qb*16 + g*4 + r4;
        F0[row][col] = acc[r4] + F1[row][col];
      }
    }
    __syncthreads();

    // ---- LN2 ----
    for (int r = wid; r < 64; r += 16){
      float x = F0[r][lane];
      float mu = wsum(x) * (1.f / 64.f);
      float dv = x - mu;
      float var = wsum(dv * dv) * (1.f / 64.f);
      float o = dv * (1.f / sqrtf(var + EPSV)) * ln2g[l*64 + lane] + ln2b[l*64 + lane];
      F1[r][lane] = o;
      ushort_t h = f2b(o);
      UH[1][r][lane] = h;
      UL[1][r][lane] = f2b(o - b2f(h));
    }
    // ---- FFN hidden ----
    stage_w1024(WH, WL, w_1, t);
    { f32x4 acc; mm16(UH[1], UL[1], WH, WL, qb, cb, li, g, acc);
      int col = cb*16 + li;
      float bb = b1[l*64 + col];
#pragma unroll
      for (int r4 = 0; r4 < 4; ++r4){
        int row = qb*16 + g*4 + r4;
        float hv = fmaxf(acc[r4] + bb, 0.f);
        ushort_t h = f2b(hv);
        UH[2][row][col] = h; UL[2][row][col] = f2b(hv - b2f(h));
      }
    }
    // ---- layer out -> F0 (+ U0 for next layer) ----
    stage_w1024(WH, WL, w_2, t);
    { f32x4 acc; mm16(UH[2], UL[2], WH, WL, qb, cb, li, g, acc);
      int col = cb*16 + li;
      float bb = b2[l*64 + col];
#pragma unroll
      for (int r4 = 0; r4 < 4; ++r4){
        int row = qb*16 + g*4 + r4;
        float o = (acc[r4] + bb + F1[row][col]) * s_msk[row];
        F0[row][col] = o;
        if (l == 0){
          ushort_t h = f2b(o);
          UH[0][row][col] = h; UL[0][row][col] = f2b(o - b2f(h));
        }
      }
    }
  }

  // ---- fused final LN on row 63 -> packed bf16 hi/lo E ----
  __syncthreads();
  if (wid == 0){
    float x = F0[63][lane];
    float mu = wsum(x) * (1.f / 64.f);
    float dv = x - mu;
    float var = wsum(dv * dv) * (1.f / 64.f);
    float o = dv * (1.f / sqrtf(var + EPSV)) * lnfg[lane] + lnfb[lane];
    ushort_t h = f2b(o);
    Eh[b * 64 + lane] = h;
    El[b * 64 + lane] = f2b(o - b2f(h));
  }
}

// --------------------------------------------------------------- scoring ---
// Block m: item tile it = m>>3 (64 items), batch chunk bc = m&7 (64 rows).
// bc INNER in blockIdx -> resident blocks cover consecutive item tiles of
// the SAME rows -> contiguous write windows per out row (DRAM page hits).
// B-frags pre-packed (k_pack), A-frags pre-packed (k_layers) -> zero
// conversion VALU here. C-write via per-wave LDS transpose (R6-proven).
__global__ __launch_bounds__(256, 4) void k_score(
    const ushort_t* __restrict__ Eh, const ushort_t* __restrict__ El,
    const short8* __restrict__ Tp, float* __restrict__ out){
  __shared__ float TT[4][16][68];
  const int t = threadIdx.x, lane = t & 63, w = t >> 6;  // 4 waves
  const int li = lane & 15, g = lane >> 4;
  const int m = blockIdx.x;
  const int it = m >> 3, bc = m & 7;
  const int i0 = it * 64;

  // B-frags: 16 KB sequential per block
  short8 Bh[8], Bl[8];
  const short8* tb = Tp + (size_t)it * 1024;
#pragma unroll
  for (int q = 0; q < 8; ++q){
    Bh[q] = tb[q*64 + lane];
    Bl[q] = tb[512 + q*64 + lane];
  }

  // A-frags: rows bc*64 + w*16 + li (L2-resident, 64 KB total)
  const int erow = bc*64 + w*16 + li;
  short8 Ah[2], Al[2];
#pragma unroll
  for (int kc = 0; kc < 2; ++kc){
    Ah[kc] = *(const short8*)&Eh[erow*64 + kc*32 + g*8];
    Al[kc] = *(const short8*)&El[erow*64 + kc*32 + g*8];
  }

  f32x4 acc[4];
#pragma unroll
  for (int nt = 0; nt < 4; ++nt) acc[nt] = (f32x4)(0.f);
#pragma unroll
  for (int kc = 0; kc < 2; ++kc){
#pragma unroll
    for (int nt = 0; nt < 4; ++nt)
      acc[nt] = __builtin_amdgcn_mfma_f32_16x16x32_bf16(Ah[kc], Bh[nt*2+kc], acc[nt], 0, 0, 0);
#pragma unroll
    for (int nt = 0; nt < 4; ++nt)
      acc[nt] = __builtin_amdgcn_mfma_f32_16x16x32_bf16(Ah[kc], Bl[nt*2+kc], acc[nt], 0, 0, 0);
#pragma unroll
    for (int nt = 0; nt < 4; ++nt)
      acc[nt] = __builtin_amdgcn_mfma_f32_16x16x32_bf16(Al[kc], Bh[nt*2+kc], acc[nt], 0, 0, 0);
  }

  // per-wave LDS transpose -> float4 coalesced stores
#pragma unroll
  for (int nt = 0; nt < 4; ++nt)
#pragma unroll
    for (int r = 0; r < 4; ++r)
      TT[w][g*4 + r][nt*16 + li] = acc[nt][r];
  asm volatile("s_waitcnt lgkmcnt(0)" ::: "memory");
  __builtin_amdgcn_sched_barrier(0);
#pragma unroll
  for (int k = 0; k < 4; ++k){
    float4 v = *(const float4*)&TT[w][4*k + g][4*li];
    int grow = bc*64 + w*16 + 4*k + g;
    *(float4*)&out[(size_t)grow * NITEMS + i0 + 4*li] = v;
  }
  __builtin_amdgcn_sched_barrier(0);
}

// ----------------------------------------------------------------- launch --
extern "C" void kernel_launch(void* const* d_in, const int* in_sizes, int n_in,
                              void* d_out, int out_size, void* d_ws, size_t ws_size,
                              hipStream_t stream){
  const int*   ids      = (const int*)  d_in[0];
  const float* item_emb = (const float*)d_in[1];
  const float* pos_emb  = (const float*)d_in[2];
  const float* ln1g     = (const float*)d_in[3];
  const float* ln1b     = (const float*)d_in[4];
  const float* Wq       = (const float*)d_in[5];
  const float* bq       = (const float*)d_in[6];
  const float* Wk       = (const float*)d_in[7];
  const float* bk       = (const float*)d_in[8];
  const float* Wv       = (const float*)d_in[9];
  const float* bv       = (const float*)d_in[10];
  const float* ln2g     = (const float*)d_in[11];
  const float* ln2b     = (const float*)d_in[12];
  const float* W1       = (const float*)d_in[13];
  const float* b1       = (const float*)d_in[14];
  const float* W2       = (const float*)d_in[15];
  const float* b2       = (const float*)d_in[16];
  const float* lnfg     = (const float*)d_in[17];
  const float* lnfb     = (const float*)d_in[18];
  const float* items    = (const float*)d_in[19];
  float* out = (float*)d_out;

  float*    seq = (float*)d_ws;                                   // 8 MB
  ushort_t* Ehp = (ushort_t*)((char*)d_ws + (8u << 20));          // 64 KB
  ushort_t* Elp = Ehp + 512 * 64;                                 // 64 KB
  short8*   Tp  = (short8*)((char*)d_ws + (16u << 20));           // 51.2 MB

  k_embed<<<2048, 256, 0, stream>>>(ids, item_emb, pos_emb, seq);
  k_pack<<<3125, 256, 0, stream>>>(items, Tp);
  k_layers<<<Bsz, 1024, 0, stream>>>(seq, ids,
      ln1g, ln1b, Wq, bq, Wk, bk, Wv, bv,
      ln2g, ln2b, W1, b1, W2, b2, lnfg, lnfb, Ehp, Elp);
  k_score<<<25000, 256, 0, stream>>>(Ehp, Elp, Tp, out);
}

// Round 9
// 197.543 us; speedup vs baseline: 1.2899x; 1.2899x over previous
//
#include <hip/hip_runtime.h>
#include <cstddef>

// SASRec inference. Round 9: k_score rebuilt — 128-item tile staged ONCE into
// LDS in MFMA fragment order (no pack kernel, no re-read), A-frags double-
// buffered from L2-hot E, 512B-contiguous per-row stores (full-line bursts to
// enable L2 write-allocate elision). k_embed/k_layers unchanged from R8.

#define NITEMS 200000
#define Bsz 512
#define Ssz 64
#define Dsz 64
#define EPSV 1e-3f
#define NEGV (-4294967295.0f)   // -2^32 + 1

typedef __attribute__((ext_vector_type(8))) short short8;   // 8 bf16
typedef __attribute__((ext_vector_type(4))) float f32x4;
typedef unsigned short ushort_t;
typedef unsigned long long u64_t;

static __device__ __forceinline__ float wsum(float v){
#pragma unroll
  for (int o = 32; o > 0; o >>= 1) v += __shfl_xor(v, o, 64);
  return v;
}
static __device__ __forceinline__ float wmax(float v){
#pragma unroll
  for (int o = 32; o > 0; o >>= 1) v = fmaxf(v, __shfl_xor(v, o, 64));
  return v;
}

// bf16 round-to-nearest-even (finite inputs only)
static __device__ __forceinline__ ushort_t f2b(float f){
  unsigned u = __float_as_uint(f);
  unsigned r = u + 0x7fffu + ((u >> 16) & 1u);
  return (ushort_t)(r >> 16);
}
static __device__ __forceinline__ float b2f(ushort_t h){
  return __uint_as_float(((unsigned)h) << 16);
}

// ---------------------------------------------------------------- embed ----
__global__ __launch_bounds__(256) void k_embed(const int* __restrict__ ids,
    const float* __restrict__ item_emb, const float* __restrict__ pos_emb,
    float* __restrict__ seq){
  int e4 = blockIdx.x * 256 + threadIdx.x;      // float4 index over [B*S][16]
  int d4 = e4 & 15, bs = e4 >> 4, s = bs & 63;
  int id = ids[bs];
  float4 r = make_float4(0.f, 0.f, 0.f, 0.f);
  if (id != NITEMS){
    float4 a = ((const float4*)(item_emb + (size_t)id * 64))[d4];
    float4 p = ((const float4*)(pos_emb + s * 64))[d4];
    r = make_float4(a.x + p.x, a.y + p.y, a.z + p.z, a.w + p.w);
  }
  ((float4*)seq)[e4] = r;
}

// ------------------------------------------------------ fused block layers --
static __device__ __forceinline__ void stage_w1024(ushort_t WH[64][72],
    ushort_t WL[64][72], float4 r0, int t){
  __syncthreads();                 // fence previous consumers of WH/WL
  int k0 = t >> 4, n0 = (t & 15) * 4;
  float f0[4] = {r0.x, r0.y, r0.z, r0.w};
#pragma unroll
  for (int j = 0; j < 4; ++j){
    ushort_t h = f2b(f0[j]);
    WH[n0 + j][k0] = h;
    WL[n0 + j][k0] = f2b(f0[j] - b2f(h));
  }
  __syncthreads();
}

static __device__ __forceinline__ void mm16(
    const ushort_t (*__restrict__ Ah)[72], const ushort_t (*__restrict__ Al)[72],
    const ushort_t (*__restrict__ Bh)[72], const ushort_t (*__restrict__ Bl)[72],
    int qb, int cb, int li, int g, f32x4& acc){
  acc = (f32x4)(0.f);
#pragma unroll
  for (int kc = 0; kc < 2; ++kc){
    short8 ah = *(const short8*)&Ah[qb*16 + li][kc*32 + g*8];
    short8 al = *(const short8*)&Al[qb*16 + li][kc*32 + g*8];
    short8 bh = *(const short8*)&Bh[cb*16 + li][kc*32 + g*8];
    short8 bl = *(const short8*)&Bl[cb*16 + li][kc*32 + g*8];
    acc = __builtin_amdgcn_mfma_f32_16x16x32_bf16(ah, bh, acc, 0, 0, 0);
    acc = __builtin_amdgcn_mfma_f32_16x16x32_bf16(ah, bl, acc, 0, 0, 0);
    acc = __builtin_amdgcn_mfma_f32_16x16x32_bf16(al, bh, acc, 0, 0, 0);
  }
}

__global__ __launch_bounds__(1024) void k_layers(const float* __restrict__ seq_g,
    const int* __restrict__ ids,
    const float* __restrict__ ln1g, const float* __restrict__ ln1b,
    const float* __restrict__ Wq, const float* __restrict__ bq,
    const float* __restrict__ Wk, const float* __restrict__ bk,
    const float* __restrict__ Wv, const float* __restrict__ bv,
    const float* __restrict__ ln2g, const float* __restrict__ ln2b,
    const float* __restrict__ W1, const float* __restrict__ b1,
    const float* __restrict__ W2, const float* __restrict__ b2,
    const float* __restrict__ lnfg, const float* __restrict__ lnfb,
    ushort_t* __restrict__ Eh, ushort_t* __restrict__ El){
  __shared__ float F0[64][68];   // seq -> scores -> x -> layer-out (f32)
  __shared__ float F1[64][68];   // LN1/LN2 residuals
  __shared__ ushort_t UH[5][64][72], UL[5][64][72];
  __shared__ ushort_t WH[64][72], WL[64][72];
  __shared__ float s_msk[64];

  const int t = threadIdx.x;
  const int lane = t & 63, wid = t >> 6;        // 16 waves
  const int li = lane & 15, g = lane >> 4;
  const int qb = wid & 3, cb = wid >> 2;
  const int b = blockIdx.x;
  const float* seq_b = seq_g + (size_t)b * Ssz * Dsz;

  // ---- phase 0: load seq -> F0 (f32) + U0 (bf16 h/l) ----
  {
    int r = t >> 4, c = (t & 15) * 4;
    float4 v = ((const float4*)seq_b)[t];
    *(float4*)&F0[r][c] = v;
    float f[4] = {v.x, v.y, v.z, v.w};
#pragma unroll
    for (int j = 0; j < 4; ++j){
      ushort_t h = f2b(f[j]);
      UH[0][r][c + j] = h;
      UL[0][r][c + j] = f2b(f[j] - b2f(h));
    }
  }
  if (t < 64) s_msk[t] = (ids[b * Ssz + t] != NITEMS) ? 1.f : 0.f;

  const int k0 = t >> 4, n0 = (t & 15) * 4;

  for (int l = 0; l < 2; ++l){
    float4 w_q = *(const float4*)&Wq[l*4096 + k0*64 + n0];
    float4 w_k = *(const float4*)&Wk[l*4096 + k0*64 + n0];
    float4 w_v = *(const float4*)&Wv[l*4096 + k0*64 + n0];
    float4 w_1 = *(const float4*)&W1[l*4096 + k0*64 + n0];
    float4 w_2 = *(const float4*)&W2[l*4096 + k0*64 + n0];

    __syncthreads();

    // ---- LN1 ----
    for (int r = wid; r < 64; r += 16){
      float x = F0[r][lane];
      float mu = wsum(x) * (1.f / 64.f);
      float dv = x - mu;
      float var = wsum(dv * dv) * (1.f / 64.f);
      float o = dv * (1.f / sqrtf(var + EPSV)) * ln1g[l*64 + lane] + ln1b[l*64 + lane];
      F1[r][lane] = o;
      ushort_t h = f2b(o);
      UH[1][r][lane] = h;
      UL[1][r][lane] = f2b(o - b2f(h));
    }

    // ---- Q ----
    stage_w1024(WH, WL, w_q, t);
    { f32x4 acc; mm16(UH[1], UL[1], WH, WL, qb, cb, li, g, acc);
      int col = cb*16 + li;
      float bb = bq[l*64 + col];
#pragma unroll
      for (int r4 = 0; r4 < 4; ++r4){
        int row = qb*16 + g*4 + r4;
        float qv = acc[r4] + bb;
        ushort_t h = f2b(qv);
        UH[2][row][col] = h; UL[2][row][col] = f2b(qv - b2f(h));
      }
    }
    // ---- K ----
    stage_w1024(WH, WL, w_k, t);
    { f32x4 acc; mm16(UH[0], UL[0], WH, WL, qb, cb, li, g, acc);
      int col = cb*16 + li;
      float bb = bk[l*64 + col];
#pragma unroll
      for (int r4 = 0; r4 < 4; ++r4){
        int row = qb*16 + g*4 + r4;
        float kv = acc[r4] + bb;
        ushort_t h = f2b(kv);
        UH[3][row][col] = h; UL[3][row][col] = f2b(kv - b2f(h));
      }
    }
    // ---- V (transposed) ----
    stage_w1024(WH, WL, w_v, t);
    { f32x4 acc; mm16(UH[0], UL[0], WH, WL, qb, cb, li, g, acc);
      int col = cb*16 + li;
      float bb = bv[l*64 + col];
#pragma unroll
      for (int r4 = 0; r4 < 4; ++r4){
        int row = qb*16 + g*4 + r4;
        float vv = acc[r4] + bb;
        ushort_t h = f2b(vv);
        UH[4][col][row] = h; UL[4][col][row] = f2b(vv - b2f(h));
      }
    }
    __syncthreads();

    // ---- scores ----
    { f32x4 acc; mm16(UH[2], UL[2], UH[3], UL[3], qb, cb, li, g, acc);
      int col = cb*16 + li;
#pragma unroll
      for (int r4 = 0; r4 < 4; ++r4)
        F0[qb*16 + g*4 + r4][col] = acc[r4];
    }
    __syncthreads();

    // ---- masked softmax ----
    for (int r = wid; r < 64; r += 16){
      float raw = F0[r][lane];
      bool valid = (lane <= r) && (s_msk[lane] != 0.f);
      float sc = valid ? raw * 0.125f : NEGV;
      float m = wmax(sc);
      float e = __expf(sc - m);
      float ssumv = wsum(e);
      float p = (e / ssumv) * s_msk[r];
      ushort_t h = f2b(p);
      UH[0][r][lane] = h;
      UL[0][r][lane] = f2b(p - b2f(h));
    }
    __syncthreads();

    // ---- x = P @ V + xq ----
    { f32x4 acc; mm16(UH[0], UL[0], UH[4], UL[4], qb, cb, li, g, acc);
      int col = cb*16 + li;
#pragma unroll
      for (int r4 = 0; r4 < 4; ++r4){
        int row = qb*16 + g*4 + r4;
        F0[row][col] = acc[r4] + F1[row][col];
      }
    }
    __syncthreads();

    // ---- LN2 ----
    for (int r = wid; r < 64; r += 16){
      float x = F0[r][lane];
      float mu = wsum(x) * (1.f / 64.f);
      float dv = x - mu;
      float var = wsum(dv * dv) * (1.f / 64.f);
      float o = dv * (1.f / sqrtf(var + EPSV)) * ln2g[l*64 + lane] + ln2b[l*64 + lane];
      F1[r][lane] = o;
      ushort_t h = f2b(o);
      UH[1][r][lane] = h;
      UL[1][r][lane] = f2b(o - b2f(h));
    }
    // ---- FFN hidden ----
    stage_w1024(WH, WL, w_1, t);
    { f32x4 acc; mm16(UH[1], UL[1], WH, WL, qb, cb, li, g, acc);
      int col = cb*16 + li;
      float bb = b1[l*64 + col];
#pragma unroll
      for (int r4 = 0; r4 < 4; ++r4){
        int row = qb*16 + g*4 + r4;
        float hv = fmaxf(acc[r4] + bb, 0.f);
        ushort_t h = f2b(hv);
        UH[2][row][col] = h; UL[2][row][col] = f2b(hv - b2f(h));
      }
    }
    // ---- layer out -> F0 (+ U0 for next layer) ----
    stage_w1024(WH, WL, w_2, t);
    { f32x4 acc; mm16(UH[2], UL[2], WH, WL, qb, cb, li, g, acc);
      int col = cb*16 + li;
      float bb = b2[l*64 + col];
#pragma unroll
      for (int r4 = 0; r4 < 4; ++r4){
        int row = qb*16 + g*4 + r4;
        float o = (acc[r4] + bb + F1[row][col]) * s_msk[row];
        F0[row][col] = o;
        if (l == 0){
          ushort_t h = f2b(o);
          UH[0][row][col] = h; UL[0][row][col] = f2b(o - b2f(h));
        }
      }
    }
  }

  // ---- fused final LN on row 63 -> packed bf16 hi/lo E ----
  __syncthreads();
  if (wid == 0){
    float x = F0[63][lane];
    float mu = wsum(x) * (1.f / 64.f);
    float dv = x - mu;
    float var = wsum(dv * dv) * (1.f / 64.f);
    float o = dv * (1.f / sqrtf(var + EPSV)) * lnfg[lane] + lnfb[lane];
    ushort_t h = f2b(o);
    Eh[b * 64 + lane] = h;
    El[b * 64 + lane] = f2b(o - b2f(h));
  }
}

// --------------------------------------------------------------- scoring ---
// Block: 128-item tile x all 512 batch rows (8 chunks of 64). T staged once
// into LDS in fragment order (hi slots 0..15, lo slots 16..31); A-frags
// double-buffered from L2-hot packed E; per-row stores are one contiguous
// 512B burst (4 full 128B lines) -> L2 can elide write-allocate fills.
#define LOADA(DH, DL, c) { int er = (c)*64 + w*16 + li;                 \
  DH[0] = *(const short8*)&Eh[er*64 + g*8];                             \
  DH[1] = *(const short8*)&Eh[er*64 + 32 + g*8];                        \
  DL[0] = *(const short8*)&El[er*64 + g*8];                             \
  DL[1] = *(const short8*)&El[er*64 + 32 + g*8]; }

#define CHUNK(c, CAh, CAl, NAh, NAl, PF) {                              \
  if (PF) LOADA(NAh, NAl, (c)+1);                                       \
  f32x4 acc[8];                                                         \
  _Pragma("unroll") for (int nt = 0; nt < 8; ++nt) acc[nt] = (f32x4)(0.f); \
  _Pragma("unroll") for (int kc = 0; kc < 2; ++kc){                     \
    _Pragma("unroll") for (int nt = 0; nt < 8; ++nt){                   \
      short8 bh = TB[nt*2 + kc][lane];                                  \
      short8 bl = TB[16 + nt*2 + kc][lane];                             \
      acc[nt] = __builtin_amdgcn_mfma_f32_16x16x32_bf16(CAh[kc], bh, acc[nt], 0, 0, 0); \
      acc[nt] = __builtin_amdgcn_mfma_f32_16x16x32_bf16(CAh[kc], bl, acc[nt], 0, 0, 0); \
      acc[nt] = __builtin_amdgcn_mfma_f32_16x16x32_bf16(CAl[kc], bh, acc[nt], 0, 0, 0); \
    }}                                                                  \
  _Pragma("unroll") for (int nt = 0; nt < 8; ++nt)                      \
    _Pragma("unroll") for (int r = 0; r < 4; ++r)                       \
      TT[w][g*4 + r][nt*16 + li] = acc[nt][r];                          \
  asm volatile("s_waitcnt lgkmcnt(0)" ::: "memory");                    \
  __builtin_amdgcn_sched_barrier(0);                                    \
  _Pragma("unroll") for (int k = 0; k < 4; ++k){                        \
    int rr = 4*k + g;                                                   \
    size_t rb = (size_t)((c)*64 + w*16 + rr) * NITEMS;                  \
    _Pragma("unroll") for (int h2 = 0; h2 < 2; ++h2){                   \
      int col = i0 + li*8 + h2*4;                                       \
      if (col < NITEMS)                                                 \
        *(float4*)&out[rb + col] = *(const float4*)&TT[w][rr][li*8 + h2*4]; \
    }}                                                                  \
  __builtin_amdgcn_sched_barrier(0); }

__global__ __launch_bounds__(256) void k_score(
    const ushort_t* __restrict__ Eh, const ushort_t* __restrict__ El,
    const float* __restrict__ T, float* __restrict__ out){
  __shared__ short8 TB[32][64];     // 32 KB: frag-ordered T tile (hi/lo)
  __shared__ float TT[4][16][132];  // 33 KB: per-wave transpose tiles
  const int t = threadIdx.x, lane = t & 63, w = t >> 6;  // 4 waves
  const int li = lane & 15, g = lane >> 4;
  const int i0 = blockIdx.x * 128;

  // ---- stage T tile (128 rows) into LDS fragment order, hi/lo bf16 ----
#pragma unroll
  for (int i = 0; i < 8; ++i){
    int e4 = t + 256 * i;            // [128 rows][16 float4-cols]
    int r = e4 >> 4, c4 = e4 & 15;
    int gi = i0 + r;
    float4 v = make_float4(0.f, 0.f, 0.f, 0.f);
    if (gi < NITEMS) v = ((const float4*)(T + (size_t)gi * 64))[c4];
    int nt = r >> 4, li2 = r & 15;
    int kc = c4 >> 3, g2 = (c4 >> 1) & 3, j0 = (c4 & 1) * 4;
    float f[4] = {v.x, v.y, v.z, v.w};
    u64_t ph = 0, pl = 0;
#pragma unroll
    for (int j = 0; j < 4; ++j){
      ushort_t hh = f2b(f[j]);
      ushort_t ll = f2b(f[j] - b2f(hh));
      ph |= (u64_t)hh << (16*j);
      pl |= (u64_t)ll << (16*j);
    }
    *(u64_t*)((ushort_t*)&TB[nt*2 + kc][g2*16 + li2] + j0) = ph;
    *(u64_t*)((ushort_t*)&TB[16 + nt*2 + kc][g2*16 + li2] + j0) = pl;
  }
  __syncthreads();

  // ---- 8 batch chunks, A double-buffered ----
  short8 Ah0[2], Al0[2], Ah1[2], Al1[2];
  LOADA(Ah0, Al0, 0);
  CHUNK(0, Ah0, Al0, Ah1, Al1, 1)
  CHUNK(1, Ah1, Al1, Ah0, Al0, 1)
  CHUNK(2, Ah0, Al0, Ah1, Al1, 1)
  CHUNK(3, Ah1, Al1, Ah0, Al0, 1)
  CHUNK(4, Ah0, Al0, Ah1, Al1, 1)
  CHUNK(5, Ah1, Al1, Ah0, Al0, 1)
  CHUNK(6, Ah0, Al0, Ah1, Al1, 1)
  CHUNK(7, Ah1, Al1, Ah0, Al0, 0)
}

// ----------------------------------------------------------------- launch --
extern "C" void kernel_launch(void* const* d_in, const int* in_sizes, int n_in,
                              void* d_out, int out_size, void* d_ws, size_t ws_size,
                              hipStream_t stream){
  const int*   ids      = (const int*)  d_in[0];
  const float* item_emb = (const float*)d_in[1];
  const float* pos_emb  = (const float*)d_in[2];
  const float* ln1g     = (const float*)d_in[3];
  const float* ln1b     = (const float*)d_in[4];
  const float* Wq       = (const float*)d_in[5];
  const float* bq       = (const float*)d_in[6];
  const float* Wk       = (const float*)d_in[7];
  const float* bk       = (const float*)d_in[8];
  const float* Wv       = (const float*)d_in[9];
  const float* bv       = (const float*)d_in[10];
  const float* ln2g     = (const float*)d_in[11];
  const float* ln2b     = (const float*)d_in[12];
  const float* W1       = (const float*)d_in[13];
  const float* b1       = (const float*)d_in[14];
  const float* W2       = (const float*)d_in[15];
  const float* b2       = (const float*)d_in[16];
  const float* lnfg     = (const float*)d_in[17];
  const float* lnfb     = (const float*)d_in[18];
  const float* items    = (const float*)d_in[19];
  float* out = (float*)d_out;

  float*    seq = (float*)d_ws;                                   // 8 MB
  ushort_t* Ehp = (ushort_t*)((char*)d_ws + (8u << 20));          // 64 KB
  ushort_t* Elp = Ehp + 512 * 64;                                 // 64 KB

  k_embed<<<2048, 256, 0, stream>>>(ids, item_emb, pos_emb, seq);
  k_layers<<<Bsz, 1024, 0, stream>>>(seq, ids,
      ln1g, ln1b, Wq, bq, Wk, bk, Wv, bv,
      ln2g, ln2b, W1, b1, W2, b2, lnfg, lnfb, Ehp, Elp);
  k_score<<<1563, 256, 0, stream>>>(Ehp, Elp, items, out);
}